// Round 1
// baseline (2916.436 us; speedup 1.0000x reference)
//
#include <hip/hip_runtime.h>
#include <cstdint>

#define H_DIM 1024
#define S_LEN 256
#define B_SZ  4
#define T_ROWS 4
#define NBLK_SCAN 256
#define DOMC ((float)(1.0 - 0.9))
#define EPS_LN 1e-5f

__device__ __forceinline__ float wave_reduce_sum(float v) {
#pragma unroll
    for (int off = 32; off > 0; off >>= 1) v += __shfl_xor(v, off, 64);
    return v;
}

// ---------------------------------------------------------------------------
// GEMM: out[m][n] = relu(A[m][:] @ W[:][n] + bias[n]), M=N=K=1024.
// GATHER=true: A row m = emb[labels[m]].
// 64x64 tile per block, 256 threads, 4x4 microtile, BK=16.
// ---------------------------------------------------------------------------
template <bool GATHER>
__global__ __launch_bounds__(256) void gemm_relu_kernel(
    const float* __restrict__ A, const int* __restrict__ labels,
    const float* __restrict__ emb, const float* __restrict__ W,
    const float* __restrict__ bias, float* __restrict__ out)
{
    __shared__ float As[16][68];   // [kk][m], padded
    __shared__ float Bs[16][64];   // [kk][n]
    __shared__ int   lab[64];

    const int tid = threadIdx.x;
    const int bx = blockIdx.x & 15;
    const int by = blockIdx.x >> 4;
    const int m0 = by * 64, n0 = bx * 64;

    if (GATHER && tid < 64) lab[tid] = labels[m0 + tid];
    __syncthreads();

    const int tx = tid & 15, ty = tid >> 4;
    const int mload = tid >> 2;          // 0..63
    const int kq    = (tid & 3) * 4;     // 0,4,8,12
    const int kb    = tid >> 4;          // 0..15
    const int nb    = (tid & 15) * 4;    // 0..60

    float acc[4][4] = {};

    for (int k0 = 0; k0 < 1024; k0 += 16) {
        const float* arow;
        if (GATHER) arow = emb + (size_t)lab[mload] * 1024 + k0 + kq;
        else        arow = A   + (size_t)(m0 + mload) * 1024 + k0 + kq;
        float4 a4 = *(const float4*)arow;
        As[kq + 0][mload] = a4.x;
        As[kq + 1][mload] = a4.y;
        As[kq + 2][mload] = a4.z;
        As[kq + 3][mload] = a4.w;

        float4 b4 = *(const float4*)&W[(size_t)(k0 + kb) * 1024 + n0 + nb];
        *(float4*)&Bs[kb][nb] = b4;
        __syncthreads();

#pragma unroll
        for (int kk = 0; kk < 16; ++kk) {
            float a_[4];
#pragma unroll
            for (int i = 0; i < 4; ++i) a_[i] = As[kk][ty * 4 + i];
            float4 bv = *(const float4*)&Bs[kk][tx * 4];
            float b_[4] = {bv.x, bv.y, bv.z, bv.w};
#pragma unroll
            for (int i = 0; i < 4; ++i)
#pragma unroll
                for (int j = 0; j < 4; ++j)
                    acc[i][j] = fmaf(a_[i], b_[j], acc[i][j]);
        }
        __syncthreads();
    }

    float bias4[4];
#pragma unroll
    for (int j = 0; j < 4; ++j) bias4[j] = bias[n0 + tx * 4 + j];
#pragma unroll
    for (int i = 0; i < 4; ++i) {
        float4 o;
        o.x = fmaxf(acc[i][0] + bias4[0], 0.f);
        o.y = fmaxf(acc[i][1] + bias4[1], 0.f);
        o.z = fmaxf(acc[i][2] + bias4[2], 0.f);
        o.w = fmaxf(acc[i][3] + bias4[3], 0.f);
        *(float4*)&out[(size_t)(m0 + ty * 4 + i) * 1024 + n0 + tx * 4] = o;
    }
}

// ---------------------------------------------------------------------------
// Scan block mapping: blockIdx -> (batch b, chain pos p). Chains stay on 2 XCDs
// (assumes blockIdx%8 -> XCD round robin; perf-only heuristic).
// block owns rows t = 4p .. 4p+3 of batch b.
// ---------------------------------------------------------------------------
__device__ __forceinline__ void decode_blk(int Bb, int& b, int& p) {
    int xcd = Bb & 7;
    b = xcd >> 1;
    p = ((xcd & 1) << 5) | (Bb >> 3);
}
__device__ __forceinline__ int encode_blk(int b, int q) {
    return ((q & 31) << 3) | (2 * b + (q >> 5));
}

// Init: publish beat -1 state of each block's last row into gbuf slot 0; flags.
__global__ __launch_bounds__(256) void scan_init_kernel(
    const float* __restrict__ h0, float* __restrict__ gbuf,
    int* __restrict__ prodf, int* __restrict__ consf)
{
    const int Bb = blockIdx.x, tid = threadIdx.x;
    int b, p; decode_blk(Bb, b, p);
    const int row = b * S_LEN + p * T_ROWS + (T_ROWS - 1);
#pragma unroll
    for (int i = 0; i < 4; ++i)
        gbuf[((size_t)Bb * 4 + 0) * H_DIM + tid + 256 * i] =
            h0[(size_t)row * H_DIM + tid + 256 * i];
    if (tid == 0) { prodf[Bb] = -1; consf[Bb] = -1; }
}

// ---------------------------------------------------------------------------
// Persistent scan. 256 blocks x 256 threads, wave w handles row t=4p+w.
// Beat L: h_L[t] = LN(0.1*relu(mix) + h_{L-1}[t]) where for out-channel h:
//   h<512 : mix = prev[2h]*W[h,0] + prev[2h+1]*W[h,1] + bs[h]   (prev = row t-1)
//   h>=512: mix = curr[2h-1024]*W[h,0] + curr[2h-1023]*W[h,1] + bs[h]
//   (prev/curr zeroed when t <= L)
// ---------------------------------------------------------------------------
__global__ __launch_bounds__(256) void scan_kernel(
    const float* __restrict__ h0, float* __restrict__ hf,
    const float* __restrict__ Wsani, const float* __restrict__ bsani,
    const float* __restrict__ lnw, const float* __restrict__ lnb,
    float* __restrict__ gbuf, int* __restrict__ prodf, int* __restrict__ consf)
{
    __shared__ float sbuf[2][T_ROWS][H_DIM];   // 32 KB, double-buffered state
    const int tid = threadIdx.x;
    const int w = tid >> 6;      // wave = row-in-block
    const int l = tid & 63;
    const int Bb = blockIdx.x;
    int b, p; decode_blk(Bb, b, p);
    const int t0 = p * T_ROWS;
    const int t = t0 + w;
    const int row = b * S_LEN + t;
    int leftB = -1, rightB = -1;
    if (p > 0)  leftB  = encode_blk(b, p - 1);
    if (p < 63) rightB = encode_blk(b, p + 1);

    // loop-invariant per-lane params for h = l + 64*i
    float w0c[16], w1c[16], bsc[16], lwc[16], lbc[16];
#pragma unroll
    for (int i = 0; i < 16; ++i) {
        int h = l + 64 * i;
        w0c[i] = Wsani[2 * h]; w1c[i] = Wsani[2 * h + 1];
        bsc[i] = bsani[h]; lwc[i] = lnw[h]; lbc[i] = lnb[h];
    }
    // beat -1 state -> slot 0
#pragma unroll
    for (int i = 0; i < 16; ++i)
        sbuf[0][w][l + 64 * i] = h0[(size_t)row * H_DIM + l + 64 * i];
    __syncthreads();

    float ycur[16];
    for (int L = 0; L < S_LEN; ++L) {
        const int sp = L & 1;       // slot holding beat L-1
        const int sc = sp ^ 1;      // slot for beat L
        const bool active = (t > L);

        float pv0[8], pv1[8];
        if (active) {
            if (w == 0) {
                // t0 > L >= 0 implies p > 0: consume left block's beat L-1
                while (__hip_atomic_load(&prodf[leftB], __ATOMIC_ACQUIRE,
                                         __HIP_MEMORY_SCOPE_AGENT) < L - 1)
                    __builtin_amdgcn_s_sleep(1);
                const float2* src =
                    (const float2*)&gbuf[((size_t)leftB * 4 + (L & 3)) * H_DIM];
#pragma unroll
                for (int i = 0; i < 8; ++i) {
                    float2 u = src[l + 64 * i]; pv0[i] = u.x; pv1[i] = u.y;
                }
            } else {
                const float2* src = (const float2*)&sbuf[sp][w - 1][0];
#pragma unroll
                for (int i = 0; i < 8; ++i) {
                    float2 u = src[l + 64 * i]; pv0[i] = u.x; pv1[i] = u.y;
                }
            }
        }
        float hp[16];
#pragma unroll
        for (int i = 0; i < 16; ++i) hp[i] = sbuf[sp][w][l + 64 * i];
        float cv0[8], cv1[8];
#pragma unroll
        for (int i = 0; i < 8; ++i) {  // own-row pairs for h>=512
            float2 u = ((const float2*)&sbuf[sp][w][0])[l + 64 * i];
            cv0[i] = u.x; cv1[i] = u.y;
        }

        float v[16]; float sum = 0.f, ss = 0.f;
#pragma unroll
        for (int i = 0; i < 8; ++i) {
            float s = active ? fmaf(pv0[i], w0c[i], fmaf(pv1[i], w1c[i], bsc[i]))
                             : bsc[i];
            s = fmaxf(s, 0.f);
            float vv = fmaf(DOMC, s, hp[i]);
            v[i] = vv; sum += vv; ss = fmaf(vv, vv, ss);
        }
#pragma unroll
        for (int i = 8; i < 16; ++i) {
            float c0 = active ? cv0[i - 8] : 0.f;
            float c1 = active ? cv1[i - 8] : 0.f;
            float s = fmaf(c0, w0c[i], fmaf(c1, w1c[i], bsc[i]));
            s = fmaxf(s, 0.f);
            float vv = fmaf(DOMC, s, hp[i]);
            v[i] = vv; sum += vv; ss = fmaf(vv, vv, ss);
        }
        // consumer progress (gates left block's ring overwrite)
        if (w == 0 && l == 0)
            __hip_atomic_store(&consf[Bb], L, __ATOMIC_RELEASE,
                               __HIP_MEMORY_SCOPE_AGENT);
        // LayerNorm (biased var, matches jnp.var)
        sum = wave_reduce_sum(sum); ss = wave_reduce_sum(ss);
        const float mu = sum * (1.f / 1024.f);
        const float var = fmaf(-mu, mu, ss * (1.f / 1024.f));
        const float r = 1.f / sqrtf(var + EPS_LN);
#pragma unroll
        for (int i = 0; i < 16; ++i) {
            float o = fmaf((v[i] - mu) * r, lwc[i], lbc[i]);
            ycur[i] = o;
            sbuf[sc][w][l + 64 * i] = o;
        }
        // publish last row to right block while it still consumes
        if (w == 3 && rightB >= 0 && L <= 4 * p + 2) {
            if (L >= 3) {
                while (__hip_atomic_load(&consf[rightB], __ATOMIC_ACQUIRE,
                                         __HIP_MEMORY_SCOPE_AGENT) < L - 3)
                    __builtin_amdgcn_s_sleep(1);
            }
            float* dst = &gbuf[((size_t)Bb * 4 + ((L + 1) & 3)) * H_DIM];
#pragma unroll
            for (int i = 0; i < 16; ++i) dst[l + 64 * i] = ycur[i];
            if (l == 0)
                __hip_atomic_store(&prodf[Bb], L, __ATOMIC_RELEASE,
                                   __HIP_MEMORY_SCOPE_AGENT);
        }
        __syncthreads();
    }
#pragma unroll
    for (int i = 0; i < 16; ++i)
        hf[(size_t)row * H_DIM + l + 64 * i] = ycur[i];
}

// ---------------------------------------------------------------------------
// Loss: per (b,e) column over S: lse = logsumexp(y[b,:,e]);
// partial = sum_s x[b,s,e]*(y-lse). One wave per column.
// ---------------------------------------------------------------------------
__global__ __launch_bounds__(256) void loss_partial_kernel(
    const float* __restrict__ y, const int* __restrict__ labels,
    const float* __restrict__ emb, float* __restrict__ partials)
{
    const int tid = threadIdx.x;
    const int wv = tid >> 6, l = tid & 63;
    const int g = blockIdx.x * 4 + wv;      // 0..4095
    const int b = g >> 10, e = g & 1023;
    const float* yb = y + (size_t)b * S_LEN * H_DIM + e;

    float yv[4];
#pragma unroll
    for (int j = 0; j < 4; ++j) yv[j] = yb[(size_t)(l + 64 * j) * 1024];
    float m = fmaxf(fmaxf(yv[0], yv[1]), fmaxf(yv[2], yv[3]));
#pragma unroll
    for (int off = 32; off > 0; off >>= 1) m = fmaxf(m, __shfl_xor(m, off, 64));
    float ps = 0.f;
#pragma unroll
    for (int j = 0; j < 4; ++j) ps += expf(yv[j] - m);
    ps = wave_reduce_sum(ps);
    const float lse = m + logf(ps);

    float acc = 0.f;
#pragma unroll
    for (int j = 0; j < 4; ++j) {
        int lab = labels[b * S_LEN + l + 64 * j];
        float xv = emb[(size_t)lab * 1024 + e];
        acc += xv * (yv[j] - lse);
    }
    acc = wave_reduce_sum(acc);
    __shared__ float wsum[4];
    if (l == 0) wsum[wv] = acc;
    __syncthreads();
    if (tid == 0) partials[blockIdx.x] = (wsum[0] + wsum[1]) + (wsum[2] + wsum[3]);
}

__global__ __launch_bounds__(256) void loss_final_kernel(
    const float* __restrict__ partials, float* __restrict__ out)
{
    const int tid = threadIdx.x;
    float a = 0.f;
#pragma unroll
    for (int j = 0; j < 4; ++j) a += partials[tid + 256 * j];
    a = wave_reduce_sum(a);
    __shared__ float wsum[4];
    if ((tid & 63) == 0) wsum[tid >> 6] = a;
    __syncthreads();
    if (tid == 0)
        out[0] = -((wsum[0] + wsum[1]) + (wsum[2] + wsum[3])) * (1.f / 4096.f);
}

// ---------------------------------------------------------------------------
extern "C" void kernel_launch(void* const* d_in, const int* in_sizes, int n_in,
                              void* d_out, int out_size, void* d_ws, size_t ws_size,
                              hipStream_t stream)
{
    const int*   labels = (const int*)  d_in[0];
    const float* emb    = (const float*)d_in[1];
    const float* W_in   = (const float*)d_in[2];
    const float* b_in   = (const float*)d_in[3];
    const float* W_sani = (const float*)d_in[4];
    const float* b_sani = (const float*)d_in[5];
    const float* ln_w   = (const float*)d_in[6];
    const float* ln_b   = (const float*)d_in[7];
    const float* W_out  = (const float*)d_in[8];
    const float* b_out  = (const float*)d_in[9];
    float* out = (float*)d_out;

    float* ws = (float*)d_ws;
    float* h0       = ws;                    // 1M floats
    float* hf       = ws + (1 << 20);        // 1M
    float* yb       = ws + 2 * (1 << 20);    // 1M
    float* gbuf     = ws + 3 * (1 << 20);    // 256*4*1024 = 1M
    float* partials = ws + 4 * (1 << 20);    // 1024
    int*   prodf    = (int*)(partials + 1024);
    int*   consf    = prodf + NBLK_SCAN;

    gemm_relu_kernel<true><<<dim3(256), dim3(256), 0, stream>>>(
        nullptr, labels, emb, W_in, b_in, h0);
    scan_init_kernel<<<dim3(NBLK_SCAN), dim3(256), 0, stream>>>(
        h0, gbuf, prodf, consf);
    {
        const float* a_h0 = h0; float* a_hf = hf;
        const float* a_ws = W_sani; const float* a_bs = b_sani;
        const float* a_lw = ln_w;   const float* a_lb = ln_b;
        float* a_gb = gbuf; int* a_pf = prodf; int* a_cf = consf;
        void* args[] = { (void*)&a_h0, (void*)&a_hf, (void*)&a_ws, (void*)&a_bs,
                         (void*)&a_lw, (void*)&a_lb, (void*)&a_gb,
                         (void*)&a_pf, (void*)&a_cf };
        hipLaunchCooperativeKernel((const void*)scan_kernel,
                                   dim3(NBLK_SCAN), dim3(256), args, 0, stream);
    }
    gemm_relu_kernel<false><<<dim3(256), dim3(256), 0, stream>>>(
        hf, nullptr, emb, W_out, b_out, yb);
    loss_partial_kernel<<<dim3(1024), dim3(256), 0, stream>>>(
        yb, labels, emb, partials);
    loss_final_kernel<<<dim3(1), dim3(256), 0, stream>>>(partials, out);
}

// Round 2
// 1071.738 us; speedup vs baseline: 2.7212x; 2.7212x over previous
//
#include <hip/hip_runtime.h>
#include <cstdint>

#define H_DIM 1024
#define S_LEN 256
#define B_SZ  4
#define NBLK_SCAN 256
#define DOMC ((float)(1.0 - 0.9))
#define EPS_LN 1e-5f

typedef float v2f __attribute__((ext_vector_type(2)));

__device__ __forceinline__ float wave_reduce_sum(float v) {
#pragma unroll
    for (int off = 32; off > 0; off >>= 1) v += __shfl_xor(v, off, 64);
    return v;
}

// ---------------------------------------------------------------------------
// LLC-streamed (sc0 sc1: bypass L1+L2, coherent at Infinity Cache) transfers
// for the cross-block boundary ring. No buffer_inv / buffer_wbl2 needed.
// ---------------------------------------------------------------------------
__device__ __forceinline__ void llc_store_row(float* base, const float* h) {
    asm volatile(
        "global_store_dword %16, %0, off sc0 sc1\n\t"
        "global_store_dword %16, %1, off offset:256 sc0 sc1\n\t"
        "global_store_dword %16, %2, off offset:512 sc0 sc1\n\t"
        "global_store_dword %16, %3, off offset:768 sc0 sc1\n\t"
        "global_store_dword %16, %4, off offset:1024 sc0 sc1\n\t"
        "global_store_dword %16, %5, off offset:1280 sc0 sc1\n\t"
        "global_store_dword %16, %6, off offset:1536 sc0 sc1\n\t"
        "global_store_dword %16, %7, off offset:1792 sc0 sc1\n\t"
        "global_store_dword %16, %8, off offset:2048 sc0 sc1\n\t"
        "global_store_dword %16, %9, off offset:2304 sc0 sc1\n\t"
        "global_store_dword %16, %10, off offset:2560 sc0 sc1\n\t"
        "global_store_dword %16, %11, off offset:2816 sc0 sc1\n\t"
        "global_store_dword %16, %12, off offset:3072 sc0 sc1\n\t"
        "global_store_dword %16, %13, off offset:3328 sc0 sc1\n\t"
        "global_store_dword %16, %14, off offset:3584 sc0 sc1\n\t"
        "global_store_dword %16, %15, off offset:3840 sc0 sc1\n\t"
        "s_waitcnt vmcnt(0)"
        :: "v"(h[0]), "v"(h[1]), "v"(h[2]), "v"(h[3]),
           "v"(h[4]), "v"(h[5]), "v"(h[6]), "v"(h[7]),
           "v"(h[8]), "v"(h[9]), "v"(h[10]), "v"(h[11]),
           "v"(h[12]), "v"(h[13]), "v"(h[14]), "v"(h[15]), "v"(base)
        : "memory");
}

__device__ __forceinline__ void llc_load_pairs(
    const float* base, v2f& p0, v2f& p1, v2f& p2, v2f& p3,
    v2f& p4, v2f& p5, v2f& p6, v2f& p7) {
    asm volatile(
        "global_load_dwordx2 %0, %8, off sc0 sc1\n\t"
        "global_load_dwordx2 %1, %8, off offset:512 sc0 sc1\n\t"
        "global_load_dwordx2 %2, %8, off offset:1024 sc0 sc1\n\t"
        "global_load_dwordx2 %3, %8, off offset:1536 sc0 sc1\n\t"
        "global_load_dwordx2 %4, %8, off offset:2048 sc0 sc1\n\t"
        "global_load_dwordx2 %5, %8, off offset:2560 sc0 sc1\n\t"
        "global_load_dwordx2 %6, %8, off offset:3072 sc0 sc1\n\t"
        "global_load_dwordx2 %7, %8, off offset:3584 sc0 sc1\n\t"
        "s_waitcnt vmcnt(0)"
        : "=&v"(p0), "=&v"(p1), "=&v"(p2), "=&v"(p3),
          "=&v"(p4), "=&v"(p5), "=&v"(p6), "=&v"(p7)
        : "v"(base)
        : "memory");
}

// ---------------------------------------------------------------------------
// GEMM: out[m][n] = relu(A[m][:] @ W[:][n] + bias[n]), M=N=K=1024.
// ---------------------------------------------------------------------------
template <bool GATHER>
__global__ __launch_bounds__(256) void gemm_relu_kernel(
    const float* __restrict__ A, const int* __restrict__ labels,
    const float* __restrict__ emb, const float* __restrict__ W,
    const float* __restrict__ bias, float* __restrict__ out)
{
    __shared__ float As[16][68];
    __shared__ float Bs[16][64];
    __shared__ int   lab[64];

    const int tid = threadIdx.x;
    const int bx = blockIdx.x & 15;
    const int by = blockIdx.x >> 4;
    const int m0 = by * 64, n0 = bx * 64;

    if (GATHER && tid < 64) lab[tid] = labels[m0 + tid];
    __syncthreads();

    const int tx = tid & 15, ty = tid >> 4;
    const int mload = tid >> 2;
    const int kq    = (tid & 3) * 4;
    const int kb    = tid >> 4;
    const int nb    = (tid & 15) * 4;

    float acc[4][4] = {};

    for (int k0 = 0; k0 < 1024; k0 += 16) {
        const float* arow;
        if (GATHER) arow = emb + (size_t)lab[mload] * 1024 + k0 + kq;
        else        arow = A   + (size_t)(m0 + mload) * 1024 + k0 + kq;
        float4 a4 = *(const float4*)arow;
        As[kq + 0][mload] = a4.x;
        As[kq + 1][mload] = a4.y;
        As[kq + 2][mload] = a4.z;
        As[kq + 3][mload] = a4.w;

        float4 b4 = *(const float4*)&W[(size_t)(k0 + kb) * 1024 + n0 + nb];
        *(float4*)&Bs[kb][nb] = b4;
        __syncthreads();

#pragma unroll
        for (int kk = 0; kk < 16; ++kk) {
            float a_[4];
#pragma unroll
            for (int i = 0; i < 4; ++i) a_[i] = As[kk][ty * 4 + i];
            float4 bv = *(const float4*)&Bs[kk][tx * 4];
            float b_[4] = {bv.x, bv.y, bv.z, bv.w};
#pragma unroll
            for (int i = 0; i < 4; ++i)
#pragma unroll
                for (int j = 0; j < 4; ++j)
                    acc[i][j] = fmaf(a_[i], b_[j], acc[i][j]);
        }
        __syncthreads();
    }

    float bias4[4];
#pragma unroll
    for (int j = 0; j < 4; ++j) bias4[j] = bias[n0 + tx * 4 + j];
#pragma unroll
    for (int i = 0; i < 4; ++i) {
        float4 o;
        o.x = fmaxf(acc[i][0] + bias4[0], 0.f);
        o.y = fmaxf(acc[i][1] + bias4[1], 0.f);
        o.z = fmaxf(acc[i][2] + bias4[2], 0.f);
        o.w = fmaxf(acc[i][3] + bias4[3], 0.f);
        *(float4*)&out[(size_t)(m0 + ty * 4 + i) * 1024 + n0 + tx * 4] = o;
    }
}

// ---------------------------------------------------------------------------
// blockIdx <-> (batch, chain position). XCD-locality heuristic only.
// ---------------------------------------------------------------------------
__device__ __forceinline__ void decode_blk(int Bb, int& b, int& p) {
    int xcd = Bb & 7;
    b = xcd >> 1;
    p = ((xcd & 1) << 5) | (Bb >> 3);
}
__device__ __forceinline__ int encode_blk(int b, int q) {
    return ((q & 31) << 3) | (2 * b + (q >> 5));
}

__global__ __launch_bounds__(256) void scan_init_kernel(
    int* __restrict__ prodG, int* __restrict__ consG)
{
    const int tid = threadIdx.x;
    prodG[tid] = -2;
    consG[tid] = -2;
}

// ---------------------------------------------------------------------------
// Dataflow scan: one wave per row, state in VGPRs. Row t active for beats
// L < t (consumes row t-1's beat L-1 state), then free-running passive tail
// h <- LN(0.1*relu(b_sani) + h). Intra-block hop: LDS ring (depth 4).
// Cross-block hop: LLC-streamed global ring (depth 4) + relaxed agent flags.
// ---------------------------------------------------------------------------
__global__ __launch_bounds__(256, 1) void scan_kernel(
    const float* __restrict__ h0, float* __restrict__ hf,
    const float* __restrict__ Wsani, const float* __restrict__ bsani,
    const float* __restrict__ lnw, const float* __restrict__ lnb,
    float* __restrict__ gbuf, int* __restrict__ prodG, int* __restrict__ consG)
{
    __shared__ float ring[3][4][H_DIM];   // ring[w]: published by wave w, read by wave w+1
    __shared__ float self3[H_DIM];        // wave 3's own-state pair scratch
    __shared__ int prodL[4], consL[4];

    const int tid = threadIdx.x, w = tid >> 6, l = tid & 63;
    const int Bb = blockIdx.x;
    int b, p; decode_blk(Bb, b, p);
    const int t = 4 * p + w;
    const int row = b * S_LEN + t;
    const int leftB  = (p > 0)  ? encode_blk(b, p - 1) : -1;
    const int rightB = (p < 63) ? encode_blk(b, p + 1) : -1;

    float w0c[16], w1c[16], bsc[16], lwc[16], lbc[16], hv[16];
#pragma unroll
    for (int i = 0; i < 16; ++i) {
        int h = l + 64 * i;
        w0c[i] = Wsani[2 * h]; w1c[i] = Wsani[2 * h + 1];
        bsc[i] = bsani[h]; lwc[i] = lnw[h]; lbc[i] = lnb[h];
        hv[i] = h0[(size_t)row * H_DIM + h];
    }

    if (tid < 4) { prodL[tid] = -2; consL[tid] = -2; }
    __syncthreads();

    // ---- publish initial state (beat -1) into slot 0
    if (w < 3) {
#pragma unroll
        for (int i = 0; i < 16; ++i) ring[w][0][l + 64 * i] = hv[i];
        __threadfence_block();
        if (l == 0) ((volatile int*)prodL)[w] = -1;
    } else {
        if (rightB >= 0) {
            float* dst = gbuf + ((size_t)Bb * 4 + 0) * H_DIM + l;
            llc_store_row(dst, hv);
            if (l == 0)
                __hip_atomic_store(&prodG[Bb], -1, __ATOMIC_RELAXED,
                                   __HIP_MEMORY_SCOPE_AGENT);
        }
#pragma unroll
        for (int i = 0; i < 16; ++i) self3[l + 64 * i] = hv[i];
    }

    const float inv1024 = 1.f / 1024.f;
    float vv[16];

    for (int L = 0; L < S_LEN; ++L) {
        const bool active = (L < t);
        if (active) {
            v2f pv[8];
            if (w == 0) {
                // cross-block input: poll relaxed agent flag, then LLC loads
                int f;
                do {
                    int ff = 0;
                    if (l == 0)
                        ff = __hip_atomic_load(&prodG[leftB], __ATOMIC_RELAXED,
                                               __HIP_MEMORY_SCOPE_AGENT);
                    f = __shfl(ff, 0, 64);
                    if (f < L - 1) __builtin_amdgcn_s_sleep(1);
                } while (f < L - 1);
                const float* src =
                    gbuf + ((size_t)leftB * 4 + (L & 3)) * H_DIM + 2 * l;
                llc_load_pairs(src, pv[0], pv[1], pv[2], pv[3],
                                    pv[4], pv[5], pv[6], pv[7]);
                if (l == 0)
                    __hip_atomic_store(&consG[Bb], L - 1, __ATOMIC_RELAXED,
                                       __HIP_MEMORY_SCOPE_AGENT);
            } else {
                while (((volatile int*)prodL)[w - 1] < L - 1) {}
                const float* srcr = &ring[w - 1][L & 3][0];
#pragma unroll
                for (int j = 0; j < 8; ++j)
                    pv[j] = *(const v2f*)&srcr[2 * l + 128 * j];
                if (l == 0) ((volatile int*)consL)[w] = L - 1;
            }
            // own-state pairs (beat L-1) from own published slot / scratch
            v2f cv[8];
            {
                const float* srcc = (w < 3) ? &ring[w][L & 3][0] : &self3[0];
#pragma unroll
                for (int j = 0; j < 8; ++j)
                    cv[j] = *(const v2f*)&srcc[2 * l + 128 * j];
            }
#pragma unroll
            for (int i = 0; i < 8; ++i) {
                float s = fmaf(pv[i].x, w0c[i], fmaf(pv[i].y, w1c[i], bsc[i]));
                s = fmaxf(s, 0.f);
                vv[i] = fmaf(DOMC, s, hv[i]);
            }
#pragma unroll
            for (int i = 8; i < 16; ++i) {
                float s = fmaf(cv[i - 8].x, w0c[i],
                               fmaf(cv[i - 8].y, w1c[i], bsc[i]));
                s = fmaxf(s, 0.f);
                vv[i] = fmaf(DOMC, s, hv[i]);
            }
        } else {
            // passive tail: neighbor-independent self-recurrence
#pragma unroll
            for (int i = 0; i < 16; ++i) {
                float s = fmaxf(bsc[i], 0.f);
                vv[i] = fmaf(DOMC, s, hv[i]);
            }
        }
        // LayerNorm
        float sum = 0.f, ss = 0.f;
#pragma unroll
        for (int i = 0; i < 16; ++i) { sum += vv[i]; ss = fmaf(vv[i], vv[i], ss); }
        sum = wave_reduce_sum(sum); ss = wave_reduce_sum(ss);
        const float mu = sum * inv1024;
        const float var = fmaf(-mu, mu, ss * inv1024);
        const float r = 1.f / sqrtf(var + EPS_LN);
#pragma unroll
        for (int i = 0; i < 16; ++i)
            hv[i] = fmaf((vv[i] - mu) * r, lwc[i], lbc[i]);

        // publish beat L (only active beats feed anyone)
        if (active) {
            if (w < 3) {
                if (L >= 3) while (((volatile int*)consL)[w + 1] < L - 4) {}
                float* dstr = &ring[w][(L + 1) & 3][0];
#pragma unroll
                for (int i = 0; i < 16; ++i) dstr[l + 64 * i] = hv[i];
                __threadfence_block();
                if (l == 0) ((volatile int*)prodL)[w] = L;
            } else {
                if (rightB >= 0) {
                    if (L >= 3) {
                        int f;
                        do {
                            int ff = 0;
                            if (l == 0)
                                ff = __hip_atomic_load(&consG[rightB],
                                                       __ATOMIC_RELAXED,
                                                       __HIP_MEMORY_SCOPE_AGENT);
                            f = __shfl(ff, 0, 64);
                            if (f < L - 4) __builtin_amdgcn_s_sleep(1);
                        } while (f < L - 4);
                    }
                    float* dst = gbuf + ((size_t)Bb * 4 + ((L + 1) & 3)) * H_DIM + l;
                    llc_store_row(dst, hv);
                    if (l == 0)
                        __hip_atomic_store(&prodG[Bb], L, __ATOMIC_RELAXED,
                                           __HIP_MEMORY_SCOPE_AGENT);
                }
                if (L + 1 < t) {
#pragma unroll
                    for (int i = 0; i < 16; ++i) self3[l + 64 * i] = hv[i];
                }
            }
        }
    }
#pragma unroll
    for (int i = 0; i < 16; ++i)
        hf[(size_t)row * H_DIM + l + 64 * i] = hv[i];
}

// ---------------------------------------------------------------------------
// Loss, stage 1: per-(b,e) online logsumexp over S. Coalesced row loads.
// grid = 16 blocks (b x e-chunk of 256), thread = one column.
// ---------------------------------------------------------------------------
__global__ __launch_bounds__(256) void lse_kernel(
    const float* __restrict__ y, float* __restrict__ lse)
{
    const int b = blockIdx.x >> 2, ec = blockIdx.x & 3;
    const int e = ec * 256 + threadIdx.x;
    const float* yb = y + (size_t)b * S_LEN * H_DIM + e;
    float m = -INFINITY, ps = 0.f;
#pragma unroll 4
    for (int s = 0; s < S_LEN; ++s) {
        float v = yb[(size_t)s * H_DIM];
        float mn = fmaxf(m, v);
        ps = fmaf(ps, expf(m - mn), expf(v - mn));
        m = mn;
    }
    lse[b * H_DIM + e] = m + logf(ps);
}

// Stage 2: per-(b,s) row dot: sum_e emb[lab][e]*(y[b,s,e]-lse[b,e]).
__global__ __launch_bounds__(256) void loss_row_kernel(
    const float* __restrict__ y, const int* __restrict__ labels,
    const float* __restrict__ emb, const float* __restrict__ lse,
    float* __restrict__ partials)
{
    const int bs = blockIdx.x;
    const int b = bs >> 8;
    const int lab = labels[bs];
    const float* yr = y + (size_t)bs * H_DIM;
    const float* er = emb + (size_t)lab * H_DIM;
    const float* lr = lse + b * H_DIM;
    float acc = 0.f;
#pragma unroll
    for (int i = 0; i < 4; ++i) {
        int e = threadIdx.x + 256 * i;
        acc = fmaf(er[e], yr[e] - lr[e], acc);
    }
    acc = wave_reduce_sum(acc);
    __shared__ float wsum[4];
    if ((threadIdx.x & 63) == 0) wsum[threadIdx.x >> 6] = acc;
    __syncthreads();
    if (threadIdx.x == 0)
        partials[bs] = (wsum[0] + wsum[1]) + (wsum[2] + wsum[3]);
}

__global__ __launch_bounds__(256) void loss_final_kernel(
    const float* __restrict__ partials, float* __restrict__ out)
{
    const int tid = threadIdx.x;
    float a = 0.f;
#pragma unroll
    for (int j = 0; j < 4; ++j) a += partials[tid + 256 * j];
    a = wave_reduce_sum(a);
    __shared__ float wsum[4];
    if ((tid & 63) == 0) wsum[tid >> 6] = a;
    __syncthreads();
    if (tid == 0)
        out[0] = -((wsum[0] + wsum[1]) + (wsum[2] + wsum[3])) * (1.f / 4096.f);
}

// ---------------------------------------------------------------------------
extern "C" void kernel_launch(void* const* d_in, const int* in_sizes, int n_in,
                              void* d_out, int out_size, void* d_ws, size_t ws_size,
                              hipStream_t stream)
{
    const int*   labels = (const int*)  d_in[0];
    const float* emb    = (const float*)d_in[1];
    const float* W_in   = (const float*)d_in[2];
    const float* b_in   = (const float*)d_in[3];
    const float* W_sani = (const float*)d_in[4];
    const float* b_sani = (const float*)d_in[5];
    const float* ln_w   = (const float*)d_in[6];
    const float* ln_b   = (const float*)d_in[7];
    const float* W_out  = (const float*)d_in[8];
    const float* b_out  = (const float*)d_in[9];
    float* out = (float*)d_out;

    float* ws = (float*)d_ws;
    float* h0       = ws;                    // 1M floats
    float* hf       = ws + (1 << 20);        // 1M
    float* yb       = ws + 2 * (1 << 20);    // 1M
    float* gbuf     = ws + 3 * (1 << 20);    // 256*4*1024 = 1M
    float* lse      = ws + 4 * (1 << 20);    // 4096
    float* partials = lse + 4096;            // 1024
    int*   prodG    = (int*)(partials + 1024);
    int*   consG    = prodG + NBLK_SCAN;

    gemm_relu_kernel<true><<<dim3(256), dim3(256), 0, stream>>>(
        nullptr, labels, emb, W_in, b_in, h0);
    scan_init_kernel<<<dim3(1), dim3(256), 0, stream>>>(prodG, consG);
    {
        const float* a_h0 = h0; float* a_hf = hf;
        const float* a_ws = W_sani; const float* a_bs = b_sani;
        const float* a_lw = ln_w;   const float* a_lb = ln_b;
        float* a_gb = gbuf; int* a_pf = prodG; int* a_cf = consG;
        void* args[] = { (void*)&a_h0, (void*)&a_hf, (void*)&a_ws, (void*)&a_bs,
                         (void*)&a_lw, (void*)&a_lb, (void*)&a_gb,
                         (void*)&a_pf, (void*)&a_cf };
        hipLaunchCooperativeKernel((const void*)scan_kernel,
                                   dim3(NBLK_SCAN), dim3(256), args, 0, stream);
    }
    gemm_relu_kernel<false><<<dim3(256), dim3(256), 0, stream>>>(
        hf, nullptr, emb, W_out, b_out, yb);
    lse_kernel<<<dim3(16), dim3(256), 0, stream>>>(yb, lse);
    loss_row_kernel<<<dim3(1024), dim3(256), 0, stream>>>(
        yb, labels, emb, lse, partials);
    loss_final_kernel<<<dim3(1), dim3(256), 0, stream>>>(partials, out);
}

// Round 3
// 803.408 us; speedup vs baseline: 3.6301x; 1.3340x over previous
//
#include <hip/hip_runtime.h>
#include <cstdint>

#define H_DIM 1024
#define S_LEN 256
#define B_SZ  4
#define T_ROWS 8
#define NBLK_SCAN 128
#define GDEPTH 8
#define DOMC ((float)(1.0 - 0.9))
#define EPS_LN 1e-5f

typedef float v2f __attribute__((ext_vector_type(2)));

// ---------------------------------------------------------------------------
// DPP 64-lane all-reduce sum: 4x row_shr + bcast15 + bcast31, total in lane 63,
// broadcast via readlane. ~12 VALU ops, no DS traffic.
// ---------------------------------------------------------------------------
template <int CTRL, int RMASK, bool BC>
__device__ __forceinline__ float dpp_term(float x) {
    return __int_as_float(__builtin_amdgcn_update_dpp(
        0, __float_as_int(x), CTRL, RMASK, 0xf, BC));
}
__device__ __forceinline__ float wave_reduce_sum(float x) {
    x += dpp_term<0x111, 0xf, true>(x);   // row_shr:1
    x += dpp_term<0x112, 0xf, true>(x);   // row_shr:2
    x += dpp_term<0x114, 0xf, true>(x);   // row_shr:4
    x += dpp_term<0x118, 0xf, true>(x);   // row_shr:8
    x += dpp_term<0x142, 0xa, false>(x);  // row_bcast15 -> rows 1,3
    x += dpp_term<0x143, 0xc, false>(x);  // row_bcast31 -> rows 2,3
    return __int_as_float(__builtin_amdgcn_readlane(__float_as_int(x), 63));
}

// ---------------------------------------------------------------------------
// MALL-coherent (sc0 sc1) global ops for the cross-block boundary ring.
// ---------------------------------------------------------------------------
__device__ __forceinline__ int llc_load_int(const int* p) {
    int v;
    asm volatile("global_load_dword %0, %1, off sc0 sc1\n\ts_waitcnt vmcnt(0)"
                 : "=v"(v) : "v"(p) : "memory");
    return v;
}
__device__ __forceinline__ void llc_store_int(int* p, int v) {
    asm volatile("global_store_dword %0, %1, off sc0 sc1" :: "v"(p), "v"(v)
                 : "memory");
}
// Beat data store WITHOUT trailing wait (flag-lag protocol drains it later).
__device__ __forceinline__ void llc_store_row_nowait(float* base, const float* h) {
    asm volatile(
        "global_store_dword %16, %0, off sc0 sc1\n\t"
        "global_store_dword %16, %1, off offset:256 sc0 sc1\n\t"
        "global_store_dword %16, %2, off offset:512 sc0 sc1\n\t"
        "global_store_dword %16, %3, off offset:768 sc0 sc1\n\t"
        "global_store_dword %16, %4, off offset:1024 sc0 sc1\n\t"
        "global_store_dword %16, %5, off offset:1280 sc0 sc1\n\t"
        "global_store_dword %16, %6, off offset:1536 sc0 sc1\n\t"
        "global_store_dword %16, %7, off offset:1792 sc0 sc1\n\t"
        "global_store_dword %16, %8, off offset:2048 sc0 sc1\n\t"
        "global_store_dword %16, %9, off offset:2304 sc0 sc1\n\t"
        "global_store_dword %16, %10, off offset:2560 sc0 sc1\n\t"
        "global_store_dword %16, %11, off offset:2816 sc0 sc1\n\t"
        "global_store_dword %16, %12, off offset:3072 sc0 sc1\n\t"
        "global_store_dword %16, %13, off offset:3328 sc0 sc1\n\t"
        "global_store_dword %16, %14, off offset:3584 sc0 sc1\n\t"
        "global_store_dword %16, %15, off offset:3840 sc0 sc1"
        :: "v"(h[0]), "v"(h[1]), "v"(h[2]), "v"(h[3]),
           "v"(h[4]), "v"(h[5]), "v"(h[6]), "v"(h[7]),
           "v"(h[8]), "v"(h[9]), "v"(h[10]), "v"(h[11]),
           "v"(h[12]), "v"(h[13]), "v"(h[14]), "v"(h[15]), "v"(base)
        : "memory");
}
// Flag-lag publish: drain PREVIOUS beat's stores, release its flag, then fire
// this beat's data stores without waiting.
__device__ __forceinline__ void llc_publish(float* dbase, int* flagp,
                                            int flagval, const float* h) {
    asm volatile(
        "s_waitcnt vmcnt(0)\n\t"
        "global_store_dword %17, %18, off sc0 sc1\n\t"
        "global_store_dword %16, %0, off sc0 sc1\n\t"
        "global_store_dword %16, %1, off offset:256 sc0 sc1\n\t"
        "global_store_dword %16, %2, off offset:512 sc0 sc1\n\t"
        "global_store_dword %16, %3, off offset:768 sc0 sc1\n\t"
        "global_store_dword %16, %4, off offset:1024 sc0 sc1\n\t"
        "global_store_dword %16, %5, off offset:1280 sc0 sc1\n\t"
        "global_store_dword %16, %6, off offset:1536 sc0 sc1\n\t"
        "global_store_dword %16, %7, off offset:1792 sc0 sc1\n\t"
        "global_store_dword %16, %8, off offset:2048 sc0 sc1\n\t"
        "global_store_dword %16, %9, off offset:2304 sc0 sc1\n\t"
        "global_store_dword %16, %10, off offset:2560 sc0 sc1\n\t"
        "global_store_dword %16, %11, off offset:2816 sc0 sc1\n\t"
        "global_store_dword %16, %12, off offset:3072 sc0 sc1\n\t"
        "global_store_dword %16, %13, off offset:3328 sc0 sc1\n\t"
        "global_store_dword %16, %14, off offset:3584 sc0 sc1\n\t"
        "global_store_dword %16, %15, off offset:3840 sc0 sc1"
        :: "v"(h[0]), "v"(h[1]), "v"(h[2]), "v"(h[3]),
           "v"(h[4]), "v"(h[5]), "v"(h[6]), "v"(h[7]),
           "v"(h[8]), "v"(h[9]), "v"(h[10]), "v"(h[11]),
           "v"(h[12]), "v"(h[13]), "v"(h[14]), "v"(h[15]),
           "v"(dbase), "v"(flagp), "v"(flagval)
        : "memory");
}
__device__ __forceinline__ void llc_release(int* flagp, int flagval) {
    asm volatile("s_waitcnt vmcnt(0)\n\t"
                 "global_store_dword %0, %1, off sc0 sc1"
                 :: "v"(flagp), "v"(flagval) : "memory");
}
__device__ __forceinline__ void llc_load_pairs(
    const float* base, v2f& p0, v2f& p1, v2f& p2, v2f& p3,
    v2f& p4, v2f& p5, v2f& p6, v2f& p7) {
    asm volatile(
        "global_load_dwordx2 %0, %8, off sc0 sc1\n\t"
        "global_load_dwordx2 %1, %8, off offset:512 sc0 sc1\n\t"
        "global_load_dwordx2 %2, %8, off offset:1024 sc0 sc1\n\t"
        "global_load_dwordx2 %3, %8, off offset:1536 sc0 sc1\n\t"
        "global_load_dwordx2 %4, %8, off offset:2048 sc0 sc1\n\t"
        "global_load_dwordx2 %5, %8, off offset:2560 sc0 sc1\n\t"
        "global_load_dwordx2 %6, %8, off offset:3072 sc0 sc1\n\t"
        "global_load_dwordx2 %7, %8, off offset:3584 sc0 sc1\n\t"
        "s_waitcnt vmcnt(0)"
        : "=&v"(p0), "=&v"(p1), "=&v"(p2), "=&v"(p3),
          "=&v"(p4), "=&v"(p5), "=&v"(p6), "=&v"(p7)
        : "v"(base)
        : "memory");
}

// ---------------------------------------------------------------------------
// GEMM: out[m][n] = relu(A[m][:] @ W[:][n] + bias[n]), M=N=K=1024.
// ---------------------------------------------------------------------------
template <bool GATHER>
__global__ __launch_bounds__(256) void gemm_relu_kernel(
    const float* __restrict__ A, const int* __restrict__ labels,
    const float* __restrict__ emb, const float* __restrict__ W,
    const float* __restrict__ bias, float* __restrict__ out)
{
    __shared__ float As[16][68];
    __shared__ float Bs[16][64];
    __shared__ int   lab[64];

    const int tid = threadIdx.x;
    const int bx = blockIdx.x & 15;
    const int by = blockIdx.x >> 4;
    const int m0 = by * 64, n0 = bx * 64;

    if (GATHER && tid < 64) lab[tid] = labels[m0 + tid];
    __syncthreads();

    const int tx = tid & 15, ty = tid >> 4;
    const int mload = tid >> 2;
    const int kq    = (tid & 3) * 4;
    const int kb    = tid >> 4;
    const int nb    = (tid & 15) * 4;

    float acc[4][4] = {};

    for (int k0 = 0; k0 < 1024; k0 += 16) {
        const float* arow;
        if (GATHER) arow = emb + (size_t)lab[mload] * 1024 + k0 + kq;
        else        arow = A   + (size_t)(m0 + mload) * 1024 + k0 + kq;
        float4 a4 = *(const float4*)arow;
        As[kq + 0][mload] = a4.x;
        As[kq + 1][mload] = a4.y;
        As[kq + 2][mload] = a4.z;
        As[kq + 3][mload] = a4.w;

        float4 b4 = *(const float4*)&W[(size_t)(k0 + kb) * 1024 + n0 + nb];
        *(float4*)&Bs[kb][nb] = b4;
        __syncthreads();

#pragma unroll
        for (int kk = 0; kk < 16; ++kk) {
            float a_[4];
#pragma unroll
            for (int i = 0; i < 4; ++i) a_[i] = As[kk][ty * 4 + i];
            float4 bv = *(const float4*)&Bs[kk][tx * 4];
            float b_[4] = {bv.x, bv.y, bv.z, bv.w};
#pragma unroll
            for (int i = 0; i < 4; ++i)
#pragma unroll
                for (int j = 0; j < 4; ++j)
                    acc[i][j] = fmaf(a_[i], b_[j], acc[i][j]);
        }
        __syncthreads();
    }

    float bias4[4];
#pragma unroll
    for (int j = 0; j < 4; ++j) bias4[j] = bias[n0 + tx * 4 + j];
#pragma unroll
    for (int i = 0; i < 4; ++i) {
        float4 o;
        o.x = fmaxf(acc[i][0] + bias4[0], 0.f);
        o.y = fmaxf(acc[i][1] + bias4[1], 0.f);
        o.z = fmaxf(acc[i][2] + bias4[2], 0.f);
        o.w = fmaxf(acc[i][3] + bias4[3], 0.f);
        *(float4*)&out[(size_t)(m0 + ty * 4 + i) * 1024 + n0 + tx * 4] = o;
    }
}

__global__ __launch_bounds__(256) void scan_init_kernel(
    int* __restrict__ prodG, int* __restrict__ consG)
{
    const int tid = threadIdx.x;
    if (tid < NBLK_SCAN) { prodG[tid * 16] = -2; consG[tid * 16] = -2; }
}

// ---------------------------------------------------------------------------
// Dataflow scan: 128 blocks x 512 threads (8 waves = 8 rows). Row t active for
// beats L < t, then free-running passive tail. Intra-block: LDS rings depth 2.
// Cross-block: global ring depth 8, sc0sc1 stores, flag-lag release protocol.
// ---------------------------------------------------------------------------
__global__ __launch_bounds__(512, 1) void scan_kernel(
    const float* __restrict__ h0, float* __restrict__ hf,
    const float* __restrict__ Wsani, const float* __restrict__ bsani,
    const float* __restrict__ lnw, const float* __restrict__ lnb,
    float* __restrict__ gbuf, int* __restrict__ prodG, int* __restrict__ consG)
{
    __shared__ float ring[7][2][H_DIM];   // 56 KB: ring[w] written by wave w
    __shared__ float self7[H_DIM];        // wave 7 own-pair scratch
    __shared__ int prodL[8], consL[8];

    const int tid = threadIdx.x, w = tid >> 6, l = tid & 63;
    const int Bb = blockIdx.x;
    const int b = Bb >> 5, p = Bb & 31;
    const int t = T_ROWS * p + w;
    const int row = b * S_LEN + t;
    const int leftB = Bb - 1, rightB = Bb + 1;
    const bool hasR = (p < 31);

    float w0c[16], w1c[16], bsc[16], lwc[16], lbc[16], hv[16];
#pragma unroll
    for (int i = 0; i < 16; ++i) {
        int h = l + 64 * i;
        w0c[i] = Wsani[2 * h]; w1c[i] = Wsani[2 * h + 1];
        bsc[i] = bsani[h]; lwc[i] = lnw[h]; lbc[i] = lnb[h];
        hv[i] = h0[(size_t)row * H_DIM + h];
    }

    if (tid < 8) { prodL[tid] = -2; consL[tid] = -2; }
    __syncthreads();

    // publish beat -1: LDS slot 1 / global slot 7 (no flag yet: flag-lag)
    if (w < 7) {
#pragma unroll
        for (int i = 0; i < 16; ++i) ring[w][1][l + 64 * i] = hv[i];
        __threadfence_block();
        if (l == 0) ((volatile int*)prodL)[w] = -1;
    } else {
        if (hasR)
            llc_store_row_nowait(gbuf + ((size_t)Bb * GDEPTH + 7) * H_DIM + l, hv);
#pragma unroll
        for (int i = 0; i < 16; ++i) self7[l + 64 * i] = hv[i];
    }

    const float inv1024 = 1.f / 1024.f;
    int consGcache = -2;
    float vv[16];

    for (int L = 0; L < S_LEN; ++L) {
        const bool active = (L < t);
        if (active) {
            v2f pv[8], cv[8];
            if (w == 0) {
                const int* fp = prodG + leftB * 16;
                int f = llc_load_int(fp);
                while (f < L - 1) { __builtin_amdgcn_s_sleep(1); f = llc_load_int(fp); }
                const float* src =
                    gbuf + ((size_t)leftB * GDEPTH + ((L - 1) & 7)) * H_DIM + 2 * l;
                llc_load_pairs(src, pv[0], pv[1], pv[2], pv[3],
                                    pv[4], pv[5], pv[6], pv[7]);
                llc_store_int(consG + Bb * 16, L - 1);
                const float* srcc = &ring[0][(L - 1) & 1][0];
#pragma unroll
                for (int j = 0; j < 8; ++j)
                    cv[j] = *(const v2f*)&srcc[2 * l + 128 * j];
            } else {
                int spin = 0;
                while (((volatile int*)prodL)[w - 1] < L - 1)
                    { if (++spin > 8) __builtin_amdgcn_s_sleep(1); }
                const float* srcp = &ring[w - 1][(L - 1) & 1][0];
#pragma unroll
                for (int j = 0; j < 8; ++j)
                    pv[j] = *(const v2f*)&srcp[2 * l + 128 * j];
                const float* srcc = (w < 7) ? &ring[w][(L - 1) & 1][0] : &self7[0];
#pragma unroll
                for (int j = 0; j < 8; ++j)
                    cv[j] = *(const v2f*)&srcc[2 * l + 128 * j];
                if (l == 0) ((volatile int*)consL)[w] = L - 1;
            }
#pragma unroll
            for (int i = 0; i < 8; ++i) {
                float s = fmaf(pv[i].x, w0c[i], fmaf(pv[i].y, w1c[i], bsc[i]));
                s = fmaxf(s, 0.f);
                vv[i] = fmaf(DOMC, s, hv[i]);
            }
#pragma unroll
            for (int i = 8; i < 16; ++i) {
                float s = fmaf(cv[i - 8].x, w0c[i],
                               fmaf(cv[i - 8].y, w1c[i], bsc[i]));
                s = fmaxf(s, 0.f);
                vv[i] = fmaf(DOMC, s, hv[i]);
            }
        } else {
#pragma unroll
            for (int i = 0; i < 16; ++i) {
                float s = fmaxf(bsc[i], 0.f);
                vv[i] = fmaf(DOMC, s, hv[i]);
            }
        }
        float sum = 0.f, ss = 0.f;
#pragma unroll
        for (int i = 0; i < 16; ++i) { sum += vv[i]; ss = fmaf(vv[i], vv[i], ss); }
        sum = wave_reduce_sum(sum); ss = wave_reduce_sum(ss);
        const float mu = sum * inv1024;
        const float var = fmaf(-mu, mu, ss * inv1024);
        const float r = 1.f / sqrtf(var + EPS_LN);
#pragma unroll
        for (int i = 0; i < 16; ++i)
            hv[i] = fmaf((vv[i] - mu) * r, lwc[i], lbc[i]);

        if (active) {
            if (w < 7) {
                // depth-2 ring: beat L clobbers beat L-2; consumer must have read it
                if (L >= 1) {
                    int spin = 0;
                    while (((volatile int*)consL)[w + 1] < L - 2)
                        { if (++spin > 8) __builtin_amdgcn_s_sleep(1); }
                }
#pragma unroll
                for (int i = 0; i < 16; ++i) ring[w][L & 1][l + 64 * i] = hv[i];
                __threadfence_block();
                if (l == 0) ((volatile int*)prodL)[w] = L;
            } else {
                if (hasR) {
                    if (L >= 7 && consGcache < L - GDEPTH) {
                        int c = llc_load_int(consG + rightB * 16);
                        while (c < L - GDEPTH) {
                            __builtin_amdgcn_s_sleep(1);
                            c = llc_load_int(consG + rightB * 16);
                        }
                        consGcache = c;
                    }
                    llc_publish(gbuf + ((size_t)Bb * GDEPTH + (L & 7)) * H_DIM + l,
                                prodG + Bb * 16, L - 1, hv);
                }
#pragma unroll
                for (int i = 0; i < 16; ++i) self7[l + 64 * i] = hv[i];
            }
        } else if (w == 7 && hasR && L == t) {
            llc_release(prodG + Bb * 16, t - 1);   // trailing flag release
        }
    }
#pragma unroll
    for (int i = 0; i < 16; ++i)
        hf[(size_t)row * H_DIM + l + 64 * i] = hv[i];
}

// ---------------------------------------------------------------------------
// Loss stage 1: per-(b,e) logsumexp over S, fully coalesced tile loads.
// grid = 64 blocks (4 b x 16 e-tiles of 64), 256 thr = 4 row-groups x 64 cols.
// ---------------------------------------------------------------------------
__global__ __launch_bounds__(256) void lse_kernel(
    const float* __restrict__ y, float* __restrict__ lse)
{
    const int b = blockIdx.x >> 4, et = blockIdx.x & 15;
    const int col = threadIdx.x & 63, rg = threadIdx.x >> 6;
    const int e = et * 64 + col;
    const float* yb = y + (size_t)b * S_LEN * H_DIM + e;
    float m = -INFINITY, s = 0.f;
    for (int r = rg; r < S_LEN; r += 4) {
        float v = yb[(size_t)r * H_DIM];
        float mn = fmaxf(m, v);
        s = fmaf(s, expf(m - mn), expf(v - mn));
        m = mn;
    }
    __shared__ float sm[4][64], sp[4][64];
    sm[rg][col] = m; sp[rg][col] = s;
    __syncthreads();
    if (threadIdx.x < 64) {
        const int c = threadIdx.x;
        float M = fmaxf(fmaxf(sm[0][c], sm[1][c]), fmaxf(sm[2][c], sm[3][c]));
        float S = sp[0][c] * expf(sm[0][c] - M) + sp[1][c] * expf(sm[1][c] - M)
                + sp[2][c] * expf(sm[2][c] - M) + sp[3][c] * expf(sm[3][c] - M);
        lse[b * H_DIM + et * 64 + c] = M + logf(S);
    }
}

// Stage 2: per-(b,s) row dot: sum_e emb[lab][e]*(y[b,s,e]-lse[b,e]).
__global__ __launch_bounds__(256) void loss_row_kernel(
    const float* __restrict__ y, const int* __restrict__ labels,
    const float* __restrict__ emb, const float* __restrict__ lse,
    float* __restrict__ partials)
{
    const int bs = blockIdx.x;
    const int b = bs >> 8;
    const int lab = labels[bs];
    const float* yr = y + (size_t)bs * H_DIM;
    const float* er = emb + (size_t)lab * H_DIM;
    const float* lr = lse + b * H_DIM;
    float acc = 0.f;
#pragma unroll
    for (int i = 0; i < 4; ++i) {
        int e = threadIdx.x + 256 * i;
        acc = fmaf(er[e], yr[e] - lr[e], acc);
    }
    acc = wave_reduce_sum(acc);
    __shared__ float wsum[4];
    if ((threadIdx.x & 63) == 0) wsum[threadIdx.x >> 6] = acc;
    __syncthreads();
    if (threadIdx.x == 0)
        partials[bs] = (wsum[0] + wsum[1]) + (wsum[2] + wsum[3]);
}

__global__ __launch_bounds__(256) void loss_final_kernel(
    const float* __restrict__ partials, float* __restrict__ out)
{
    const int tid = threadIdx.x;
    float a = 0.f;
#pragma unroll
    for (int j = 0; j < 4; ++j) a += partials[tid + 256 * j];
    a = wave_reduce_sum(a);
    __shared__ float wsum[4];
    if ((tid & 63) == 0) wsum[tid >> 6] = a;
    __syncthreads();
    if (tid == 0)
        out[0] = -((wsum[0] + wsum[1]) + (wsum[2] + wsum[3])) * (1.f / 4096.f);
}

// ---------------------------------------------------------------------------
extern "C" void kernel_launch(void* const* d_in, const int* in_sizes, int n_in,
                              void* d_out, int out_size, void* d_ws, size_t ws_size,
                              hipStream_t stream)
{
    const int*   labels = (const int*)  d_in[0];
    const float* emb    = (const float*)d_in[1];
    const float* W_in   = (const float*)d_in[2];
    const float* b_in   = (const float*)d_in[3];
    const float* W_sani = (const float*)d_in[4];
    const float* b_sani = (const float*)d_in[5];
    const float* ln_w   = (const float*)d_in[6];
    const float* ln_b   = (const float*)d_in[7];
    const float* W_out  = (const float*)d_in[8];
    const float* b_out  = (const float*)d_in[9];
    float* out = (float*)d_out;

    float* ws = (float*)d_ws;
    float* h0       = ws;                    // 1M floats
    float* hf       = ws + (1 << 20);        // 1M
    float* yb       = ws + 2 * (1 << 20);    // 1M
    float* gbuf     = ws + 3 * (1 << 20);    // 128*8*1024 = 1M
    float* lse      = ws + 4 * (1 << 20);    // 4096
    float* partials = lse + 4096;            // 1024
    int*   prodG    = (int*)(partials + 1024);   // 128*16 ints
    int*   consG    = prodG + NBLK_SCAN * 16;

    gemm_relu_kernel<true><<<dim3(256), dim3(256), 0, stream>>>(
        nullptr, labels, emb, W_in, b_in, h0);
    scan_init_kernel<<<dim3(1), dim3(256), 0, stream>>>(prodG, consG);
    {
        const float* a_h0 = h0; float* a_hf = hf;
        const float* a_ws = W_sani; const float* a_bs = b_sani;
        const float* a_lw = ln_w;   const float* a_lb = ln_b;
        float* a_gb = gbuf; int* a_pf = prodG; int* a_cf = consG;
        void* args[] = { (void*)&a_h0, (void*)&a_hf, (void*)&a_ws, (void*)&a_bs,
                         (void*)&a_lw, (void*)&a_lb, (void*)&a_gb,
                         (void*)&a_pf, (void*)&a_cf };
        hipLaunchCooperativeKernel((const void*)scan_kernel,
                                   dim3(NBLK_SCAN), dim3(512), args, 0, stream);
    }
    gemm_relu_kernel<false><<<dim3(256), dim3(256), 0, stream>>>(
        hf, nullptr, emb, W_out, b_out, yb);
    lse_kernel<<<dim3(64), dim3(256), 0, stream>>>(yb, lse);
    loss_row_kernel<<<dim3(1024), dim3(256), 0, stream>>>(
        yb, labels, emb, lse, partials);
    loss_final_kernel<<<dim3(1), dim3(256), 0, stream>>>(partials, out);
}

// Round 4
// 756.784 us; speedup vs baseline: 3.8537x; 1.0616x over previous
//
#include <hip/hip_runtime.h>
#include <cstdint>

#define H_DIM 1024
#define S_LEN 256
#define NBLK_SCAN 128
#define GDEPTH 16
#define DOMC ((float)(1.0 - 0.9))
#define EPS_LN 1e-5f

typedef float v2f __attribute__((ext_vector_type(2)));

// ---------------------------------------------------------------------------
// DPP 64-lane all-reduce sum.
// ---------------------------------------------------------------------------
template <int CTRL, int RMASK, bool BC>
__device__ __forceinline__ float dpp_term(float x) {
    return __int_as_float(__builtin_amdgcn_update_dpp(
        0, __float_as_int(x), CTRL, RMASK, 0xf, BC));
}
__device__ __forceinline__ float wave_reduce_sum(float x) {
    x += dpp_term<0x111, 0xf, true>(x);
    x += dpp_term<0x112, 0xf, true>(x);
    x += dpp_term<0x114, 0xf, true>(x);
    x += dpp_term<0x118, 0xf, true>(x);
    x += dpp_term<0x142, 0xa, false>(x);
    x += dpp_term<0x143, 0xc, false>(x);
    return __int_as_float(__builtin_amdgcn_readlane(__float_as_int(x), 63));
}

// ---------------------------------------------------------------------------
// MALL-coherent (sc0 sc1) global ops.
// ---------------------------------------------------------------------------
__device__ __forceinline__ int llc_load_int(const int* p) {
    int v;
    asm volatile("global_load_dword %0, %1, off sc0 sc1\n\ts_waitcnt vmcnt(0)"
                 : "=v"(v) : "v"(p) : "memory");
    return v;
}
__device__ __forceinline__ void llc_store_int(int* p, int v) {
    asm volatile("global_store_dword %0, %1, off sc0 sc1" :: "v"(p), "v"(v)
                 : "memory");
}
__device__ __forceinline__ void llc_store_row_nowait(float* base, const float* h) {
    asm volatile(
        "global_store_dword %16, %0, off sc0 sc1\n\t"
        "global_store_dword %16, %1, off offset:256 sc0 sc1\n\t"
        "global_store_dword %16, %2, off offset:512 sc0 sc1\n\t"
        "global_store_dword %16, %3, off offset:768 sc0 sc1\n\t"
        "global_store_dword %16, %4, off offset:1024 sc0 sc1\n\t"
        "global_store_dword %16, %5, off offset:1280 sc0 sc1\n\t"
        "global_store_dword %16, %6, off offset:1536 sc0 sc1\n\t"
        "global_store_dword %16, %7, off offset:1792 sc0 sc1\n\t"
        "global_store_dword %16, %8, off offset:2048 sc0 sc1\n\t"
        "global_store_dword %16, %9, off offset:2304 sc0 sc1\n\t"
        "global_store_dword %16, %10, off offset:2560 sc0 sc1\n\t"
        "global_store_dword %16, %11, off offset:2816 sc0 sc1\n\t"
        "global_store_dword %16, %12, off offset:3072 sc0 sc1\n\t"
        "global_store_dword %16, %13, off offset:3328 sc0 sc1\n\t"
        "global_store_dword %16, %14, off offset:3584 sc0 sc1\n\t"
        "global_store_dword %16, %15, off offset:3840 sc0 sc1"
        :: "v"(h[0]), "v"(h[1]), "v"(h[2]), "v"(h[3]),
           "v"(h[4]), "v"(h[5]), "v"(h[6]), "v"(h[7]),
           "v"(h[8]), "v"(h[9]), "v"(h[10]), "v"(h[11]),
           "v"(h[12]), "v"(h[13]), "v"(h[14]), "v"(h[15]), "v"(base)
        : "memory");
}
// Flag-lag-2 publish: vmcnt(16) guarantees data <= L-2 drained (beat L-1's 16
// stores may remain in flight) -> release flag L-2, fire beat-L data, no stall.
__device__ __forceinline__ void llc_publish_lag2(float* dbase, int* flagp,
                                                 int flagval, const float* h) {
    asm volatile(
        "s_waitcnt vmcnt(16)\n\t"
        "global_store_dword %17, %18, off sc0 sc1\n\t"
        "global_store_dword %16, %0, off sc0 sc1\n\t"
        "global_store_dword %16, %1, off offset:256 sc0 sc1\n\t"
        "global_store_dword %16, %2, off offset:512 sc0 sc1\n\t"
        "global_store_dword %16, %3, off offset:768 sc0 sc1\n\t"
        "global_store_dword %16, %4, off offset:1024 sc0 sc1\n\t"
        "global_store_dword %16, %5, off offset:1280 sc0 sc1\n\t"
        "global_store_dword %16, %6, off offset:1536 sc0 sc1\n\t"
        "global_store_dword %16, %7, off offset:1792 sc0 sc1\n\t"
        "global_store_dword %16, %8, off offset:2048 sc0 sc1\n\t"
        "global_store_dword %16, %9, off offset:2304 sc0 sc1\n\t"
        "global_store_dword %16, %10, off offset:2560 sc0 sc1\n\t"
        "global_store_dword %16, %11, off offset:2816 sc0 sc1\n\t"
        "global_store_dword %16, %12, off offset:3072 sc0 sc1\n\t"
        "global_store_dword %16, %13, off offset:3328 sc0 sc1\n\t"
        "global_store_dword %16, %14, off offset:3584 sc0 sc1\n\t"
        "global_store_dword %16, %15, off offset:3840 sc0 sc1"
        :: "v"(h[0]), "v"(h[1]), "v"(h[2]), "v"(h[3]),
           "v"(h[4]), "v"(h[5]), "v"(h[6]), "v"(h[7]),
           "v"(h[8]), "v"(h[9]), "v"(h[10]), "v"(h[11]),
           "v"(h[12]), "v"(h[13]), "v"(h[14]), "v"(h[15]),
           "v"(dbase), "v"(flagp), "v"(flagval)
        : "memory");
}
__device__ __forceinline__ void llc_release(int* flagp, int flagval) {
    asm volatile("s_waitcnt vmcnt(0)\n\t"
                 "global_store_dword %0, %1, off sc0 sc1"
                 :: "v"(flagp), "v"(flagval) : "memory");
}

// Async DMA of one 4 KB ring slot (global -> LDS staging), MALL-coherent.
// aux 0x11 = SC0|SC1 (gfx940+ CPol encoding). vmcnt-tracked.
__device__ __forceinline__ void dma_slot(const float* gslot, float* stg, int l) {
#pragma unroll
    for (int c = 0; c < 4; ++c)
        __builtin_amdgcn_global_load_lds(
            (const __attribute__((address_space(1))) uint32_t*)(gslot + c * 256 + l * 4),
            (__attribute__((address_space(3))) uint32_t*)(stg + c * 256),
            16, 0, 0x11);
}

// Wave-7 own-state pairs (elements 2l+128j, 2l+1+128j) via shuffles.
__device__ __forceinline__ void make_pairs(const float* hv, v2f* c7, int l) {
    const int s0 = (2 * l) & 63, s1 = (2 * l + 1) & 63;
    const bool hi = (l >= 32);
#pragma unroll
    for (int j = 0; j < 8; ++j) {
        float x0 = __shfl(hv[2 * j], s0, 64);
        float x1 = __shfl(hv[2 * j + 1], s0, 64);
        float y0 = __shfl(hv[2 * j], s1, 64);
        float y1 = __shfl(hv[2 * j + 1], s1, 64);
        c7[j].x = hi ? x1 : x0;
        c7[j].y = hi ? y1 : y0;
    }
}

// ---------------------------------------------------------------------------
// GEMM: out = relu(A @ W + bias), 1024^3, 64x64 tiles, global->reg prefetch.
// ---------------------------------------------------------------------------
template <bool GATHER>
__global__ __launch_bounds__(256) void gemm_relu_kernel(
    const float* __restrict__ A, const int* __restrict__ labels,
    const float* __restrict__ emb, const float* __restrict__ W,
    const float* __restrict__ bias, float* __restrict__ out)
{
    __shared__ float As[16][68];
    __shared__ float Bs[16][64];
    __shared__ int   lab[64];

    const int tid = threadIdx.x;
    const int bx = blockIdx.x & 15;
    const int by = blockIdx.x >> 4;
    const int m0 = by * 64, n0 = bx * 64;

    if (GATHER && tid < 64) lab[tid] = labels[m0 + tid];
    __syncthreads();

    const int tx = tid & 15, ty = tid >> 4;
    const int mload = tid >> 2;
    const int kq    = (tid & 3) * 4;
    const int kb    = tid >> 4;
    const int nb    = (tid & 15) * 4;

    const float* aBase;
    if (GATHER) aBase = emb + (size_t)lab[mload] * 1024 + kq;
    else        aBase = A   + (size_t)(m0 + mload) * 1024 + kq;
    const float* bBase = W + (size_t)kb * 1024 + n0 + nb;

    float4 a_pre = *(const float4*)aBase;
    float4 b_pre = *(const float4*)bBase;

    float acc[4][4] = {};

    for (int k0 = 0; k0 < 1024; k0 += 16) {
        As[kq + 0][mload] = a_pre.x;
        As[kq + 1][mload] = a_pre.y;
        As[kq + 2][mload] = a_pre.z;
        As[kq + 3][mload] = a_pre.w;
        *(float4*)&Bs[kb][nb] = b_pre;
        __syncthreads();

        if (k0 + 16 < 1024) {   // prefetch next tile while computing this one
            a_pre = *(const float4*)(aBase + k0 + 16);
            b_pre = *(const float4*)(bBase + (size_t)(k0 + 16) * 1024);
        }

#pragma unroll
        for (int kk = 0; kk < 16; ++kk) {
            float a_[4];
#pragma unroll
            for (int i = 0; i < 4; ++i) a_[i] = As[kk][ty * 4 + i];
            float4 bv = *(const float4*)&Bs[kk][tx * 4];
            float b_[4] = {bv.x, bv.y, bv.z, bv.w};
#pragma unroll
            for (int i = 0; i < 4; ++i)
#pragma unroll
                for (int j = 0; j < 4; ++j)
                    acc[i][j] = fmaf(a_[i], b_[j], acc[i][j]);
        }
        __syncthreads();
    }

    float bias4[4];
#pragma unroll
    for (int j = 0; j < 4; ++j) bias4[j] = bias[n0 + tx * 4 + j];
#pragma unroll
    for (int i = 0; i < 4; ++i) {
        float4 o;
        o.x = fmaxf(acc[i][0] + bias4[0], 0.f);
        o.y = fmaxf(acc[i][1] + bias4[1], 0.f);
        o.z = fmaxf(acc[i][2] + bias4[2], 0.f);
        o.w = fmaxf(acc[i][3] + bias4[3], 0.f);
        *(float4*)&out[(size_t)(m0 + ty * 4 + i) * 1024 + n0 + tx * 4] = o;
    }
}

__global__ __launch_bounds__(256) void scan_init_kernel(
    int* __restrict__ prodG, int* __restrict__ consG)
{
    const int tid = threadIdx.x;
    if (tid < NBLK_SCAN) { prodG[tid * 32] = -2; consG[tid * 32] = -2; }
}

// ---------------------------------------------------------------------------
// Dataflow scan: 128 blocks x 512 threads (8 waves = 8 rows). LDS rings depth 2
// intra-block; depth-16 global ring + async DMA prefetch at block boundaries.
// Producer (w7): flag-lag-2 publish, zero stalls. Consumer (w0): staged DMA one
// beat ahead, flag polls amortized over producer lead.
// ---------------------------------------------------------------------------
__global__ __launch_bounds__(512, 1) void scan_kernel(
    const float* __restrict__ h0, float* __restrict__ hf,
    const float* __restrict__ Wsani, const float* __restrict__ bsani,
    const float* __restrict__ lnw, const float* __restrict__ lnb,
    float* __restrict__ gbuf, int* __restrict__ prodG, int* __restrict__ consG)
{
    __shared__ float ring[7][2][H_DIM];   // 56 KB
    __shared__ float stg[H_DIM];          // 4 KB DMA staging (wave 0)
    __shared__ int prodL[8], consL[8];

    const int tid = threadIdx.x, w = tid >> 6, l = tid & 63;
    const int Bb = blockIdx.x;
    const int b = Bb >> 5, p = Bb & 31;
    const int t = 8 * p + w;
    const int row = b * S_LEN + t;
    const bool hasR = (p < 31);
    const int leftB = Bb - 1, rightB = Bb + 1;

    float w0c[16], w1c[16], bsc[16], lwc[16], lbc[16], hv[16];
#pragma unroll
    for (int i = 0; i < 16; ++i) {
        int h = l + 64 * i;
        w0c[i] = Wsani[2 * h]; w1c[i] = Wsani[2 * h + 1];
        bsc[i] = bsani[h]; lwc[i] = lnw[h]; lbc[i] = lnb[h];
        hv[i] = h0[(size_t)row * H_DIM + h];
    }

    if (tid < 8) { prodL[tid] = -2; consL[tid] = -2; }
    __syncthreads();

    v2f c7[8];
    if (w < 7) {
#pragma unroll
        for (int i = 0; i < 16; ++i) ring[w][1][l + 64 * i] = hv[i];
        __threadfence_block();
        if (l == 0) ((volatile int*)prodL)[w] = -1;
    } else {
        if (hasR)
            llc_store_row_nowait(
                gbuf + ((size_t)Bb * GDEPTH + (GDEPTH - 1)) * H_DIM + l, hv);
        make_pairs(hv, c7, l);
    }

    const float inv1024 = 1.f / 1024.f;
    int F = -2, pfL = -3, consCache = -2;
    float vv[16];

    for (int L = 0; L < S_LEN; ++L) {
        const bool active = (L < t);
        if (active) {
            v2f pv[8], cv[8];
            if (w == 0) {
                const int* fp = prodG + leftB * 32;
                if (pfL != L - 1) {   // sync fill path
                    while (F < L - 1) {
                        F = llc_load_int(fp);
                        if (F < L - 1) __builtin_amdgcn_s_sleep(1);
                    }
                    dma_slot(gbuf + ((size_t)leftB * GDEPTH +
                                     ((L - 1) & (GDEPTH - 1))) * H_DIM, stg, l);
                    pfL = L - 1;
                }
                asm volatile("s_waitcnt vmcnt(0)" ::: "memory");
#pragma unroll
                for (int j = 0; j < 8; ++j)
                    pv[j] = *(const v2f*)&stg[2 * l + 128 * j];
#pragma unroll
                for (int j = 0; j < 8; ++j)
                    cv[j] = *(const v2f*)&ring[0][(L - 1) & 1][2 * l + 128 * j];
                if (F < L) F = llc_load_int(fp);   // single refresh
                if (F >= L && L < t - 1) {          // prefetch next beat's data
                    asm volatile("s_waitcnt lgkmcnt(0)" ::: "memory");
                    dma_slot(gbuf + ((size_t)leftB * GDEPTH +
                                     (L & (GDEPTH - 1))) * H_DIM, stg, l);
                    pfL = L;
                }
                llc_store_int(consG + Bb * 32, L);  // fire & forget
            } else {
                int spin = 0;
                while (((volatile int*)prodL)[w - 1] < L - 1)
                    { if (++spin > 8) __builtin_amdgcn_s_sleep(1); }
                const float* srcp = &ring[w - 1][(L - 1) & 1][0];
#pragma unroll
                for (int j = 0; j < 8; ++j)
                    pv[j] = *(const v2f*)&srcp[2 * l + 128 * j];
                if (w < 7) {
                    const float* srcc = &ring[w][(L - 1) & 1][0];
#pragma unroll
                    for (int j = 0; j < 8; ++j)
                        cv[j] = *(const v2f*)&srcc[2 * l + 128 * j];
                } else {
#pragma unroll
                    for (int j = 0; j < 8; ++j) cv[j] = c7[j];
                }
                if (l == 0) ((volatile int*)consL)[w] = L - 1;
            }
#pragma unroll
            for (int i = 0; i < 8; ++i) {
                float s = fmaf(pv[i].x, w0c[i], fmaf(pv[i].y, w1c[i], bsc[i]));
                s = fmaxf(s, 0.f);
                vv[i] = fmaf(DOMC, s, hv[i]);
            }
#pragma unroll
            for (int i = 8; i < 16; ++i) {
                float s = fmaf(cv[i - 8].x, w0c[i],
                               fmaf(cv[i - 8].y, w1c[i], bsc[i]));
                s = fmaxf(s, 0.f);
                vv[i] = fmaf(DOMC, s, hv[i]);
            }
        } else {
#pragma unroll
            for (int i = 0; i < 16; ++i) {
                float s = fmaxf(bsc[i], 0.f);
                vv[i] = fmaf(DOMC, s, hv[i]);
            }
        }
        float sum = 0.f, ss = 0.f;
#pragma unroll
        for (int i = 0; i < 16; ++i) { sum += vv[i]; ss = fmaf(vv[i], vv[i], ss); }
        sum = wave_reduce_sum(sum); ss = wave_reduce_sum(ss);
        const float mu = sum * inv1024;
        const float var = fmaf(-mu, mu, ss * inv1024);
        const float r = 1.f / sqrtf(var + EPS_LN);
#pragma unroll
        for (int i = 0; i < 16; ++i)
            hv[i] = fmaf((vv[i] - mu) * r, lwc[i], lbc[i]);

        if (active) {
            if (w < 7) {
                if (L >= 1) {
                    int spin = 0;
                    while (((volatile int*)consL)[w + 1] < L - 2)
                        { if (++spin > 8) __builtin_amdgcn_s_sleep(1); }
                }
#pragma unroll
                for (int i = 0; i < 16; ++i) ring[w][L & 1][l + 64 * i] = hv[i];
                __threadfence_block();
                if (l == 0) ((volatile int*)prodL)[w] = L;
            } else {
                if (hasR) {
                    if (consCache < L - (GDEPTH - 3)) {
                        int c = llc_load_int(consG + rightB * 32);
                        while (c < L - (GDEPTH - 1)) {
                            __builtin_amdgcn_s_sleep(1);
                            c = llc_load_int(consG + rightB * 32);
                        }
                        consCache = c;
                    }
                    llc_publish_lag2(
                        gbuf + ((size_t)Bb * GDEPTH + (L & (GDEPTH - 1))) * H_DIM + l,
                        prodG + Bb * 32, L - 2, hv);
                }
                if (L + 1 < t) make_pairs(hv, c7, l);
            }
        } else if (w == 7 && hasR && L == t) {
            llc_release(prodG + Bb * 32, t - 1);   // trailing flag release
        }
    }
#pragma unroll
    for (int i = 0; i < 16; ++i)
        hf[(size_t)row * H_DIM + l + 64 * i] = hv[i];
}

// ---------------------------------------------------------------------------
// Loss stage 1: per-(b,e) logsumexp over S, coalesced tile loads.
// ---------------------------------------------------------------------------
__global__ __launch_bounds__(256) void lse_kernel(
    const float* __restrict__ y, float* __restrict__ lse)
{
    const int b = blockIdx.x >> 4, et = blockIdx.x & 15;
    const int col = threadIdx.x & 63, rg = threadIdx.x >> 6;
    const int e = et * 64 + col;
    const float* yb = y + (size_t)b * S_LEN * H_DIM + e;
    float m = -INFINITY, s = 0.f;
    for (int r = rg; r < S_LEN; r += 4) {
        float v = yb[(size_t)r * H_DIM];
        float mn = fmaxf(m, v);
        s = fmaf(s, expf(m - mn), expf(v - mn));
        m = mn;
    }
    __shared__ float sm[4][64], sp[4][64];
    sm[rg][col] = m; sp[rg][col] = s;
    __syncthreads();
    if (threadIdx.x < 64) {
        const int c = threadIdx.x;
        float M = fmaxf(fmaxf(sm[0][c], sm[1][c]), fmaxf(sm[2][c], sm[3][c]));
        float S = sp[0][c] * expf(sm[0][c] - M) + sp[1][c] * expf(sm[1][c] - M)
                + sp[2][c] * expf(sm[2][c] - M) + sp[3][c] * expf(sm[3][c] - M);
        lse[b * H_DIM + et * 64 + c] = M + logf(S);
    }
}

__global__ __launch_bounds__(256) void loss_row_kernel(
    const float* __restrict__ y, const int* __restrict__ labels,
    const float* __restrict__ emb, const float* __restrict__ lse,
    float* __restrict__ partials)
{
    const int bs = blockIdx.x;
    const int b = bs >> 8;
    const int lab = labels[bs];
    const float* yr = y + (size_t)bs * H_DIM;
    const float* er = emb + (size_t)lab * H_DIM;
    const float* lr = lse + b * H_DIM;
    float acc = 0.f;
#pragma unroll
    for (int i = 0; i < 4; ++i) {
        int e = threadIdx.x + 256 * i;
        acc = fmaf(er[e], yr[e] - lr[e], acc);
    }
    acc = wave_reduce_sum(acc);
    __shared__ float wsum[4];
    if ((threadIdx.x & 63) == 0) wsum[threadIdx.x >> 6] = acc;
    __syncthreads();
    if (threadIdx.x == 0)
        partials[bs] = (wsum[0] + wsum[1]) + (wsum[2] + wsum[3]);
}

__global__ __launch_bounds__(256) void loss_final_kernel(
    const float* __restrict__ partials, float* __restrict__ out)
{
    const int tid = threadIdx.x;
    float a = 0.f;
#pragma unroll
    for (int j = 0; j < 4; ++j) a += partials[tid + 256 * j];
    a = wave_reduce_sum(a);
    __shared__ float wsum[4];
    if ((tid & 63) == 0) wsum[tid >> 6] = a;
    __syncthreads();
    if (tid == 0)
        out[0] = -((wsum[0] + wsum[1]) + (wsum[2] + wsum[3])) * (1.f / 4096.f);
}

// ---------------------------------------------------------------------------
extern "C" void kernel_launch(void* const* d_in, const int* in_sizes, int n_in,
                              void* d_out, int out_size, void* d_ws, size_t ws_size,
                              hipStream_t stream)
{
    const int*   labels = (const int*)  d_in[0];
    const float* emb    = (const float*)d_in[1];
    const float* W_in   = (const float*)d_in[2];
    const float* b_in   = (const float*)d_in[3];
    const float* W_sani = (const float*)d_in[4];
    const float* b_sani = (const float*)d_in[5];
    const float* ln_w   = (const float*)d_in[6];
    const float* ln_b   = (const float*)d_in[7];
    const float* W_out  = (const float*)d_in[8];
    const float* b_out  = (const float*)d_in[9];
    float* out = (float*)d_out;

    float* ws = (float*)d_ws;
    float* h0       = ws;                    // 1M floats
    float* hf       = ws + (1 << 20);        // 1M
    float* yb       = ws + 2 * (1 << 20);    // 1M
    float* gbuf     = ws + 3 * (1 << 20);    // 128*16*1024 = 2M
    float* lse      = ws + 5 * (1 << 20);    // 4096
    float* partials = lse + 4096;            // 1024
    int*   prodG    = (int*)(partials + 1024);   // 128*32 ints
    int*   consG    = prodG + NBLK_SCAN * 32;

    gemm_relu_kernel<true><<<dim3(256), dim3(256), 0, stream>>>(
        nullptr, labels, emb, W_in, b_in, h0);
    scan_init_kernel<<<dim3(1), dim3(256), 0, stream>>>(prodG, consG);
    {
        const float* a_h0 = h0; float* a_hf = hf;
        const float* a_ws = W_sani; const float* a_bs = b_sani;
        const float* a_lw = ln_w;   const float* a_lb = ln_b;
        float* a_gb = gbuf; int* a_pf = prodG; int* a_cf = consG;
        void* args[] = { (void*)&a_h0, (void*)&a_hf, (void*)&a_ws, (void*)&a_bs,
                         (void*)&a_lw, (void*)&a_lb, (void*)&a_gb,
                         (void*)&a_pf, (void*)&a_cf };
        hipLaunchCooperativeKernel((const void*)scan_kernel,
                                   dim3(NBLK_SCAN), dim3(512), args, 0, stream);
    }
    gemm_relu_kernel<false><<<dim3(256), dim3(256), 0, stream>>>(
        hf, nullptr, emb, W_out, b_out, yb);
    lse_kernel<<<dim3(64), dim3(256), 0, stream>>>(yb, lse);
    loss_row_kernel<<<dim3(1024), dim3(256), 0, stream>>>(
        yb, labels, emb, lse, partials);
    loss_final_kernel<<<dim3(1), dim3(256), 0, stream>>>(partials, out);
}